// Round 2
// 3663.940 us; speedup vs baseline: 1.3409x; 1.3409x over previous
//
#include <hip/hip_runtime.h>
#include <hip/hip_bf16.h>

#define B_   16
#define NB   1024
#define NS   4096
#define C_   768
#define H_   12
#define DH   64
#define KTOP 128
#define CM   3072
#define EPSV 1e-5f

typedef __hip_bfloat16 bf16;
typedef __attribute__((ext_vector_type(8))) _Float16 half8;
typedef __attribute__((ext_vector_type(8))) unsigned short ushort8;
typedef __attribute__((ext_vector_type(16))) float f32x16;

__device__ __forceinline__ float bf2f(unsigned short s){
  union{unsigned int u; float f;} v; v.u = ((unsigned int)s)<<16; return v.f;
}

template<typename T> __device__ __forceinline__ float4 load4(const T* p);
template<> __device__ __forceinline__ float4 load4<float>(const float* p){ return *(const float4*)p; }
template<> __device__ __forceinline__ float4 load4<bf16>(const bf16* p){
  ushort4 u = *(const ushort4*)p;
  return make_float4(bf2f(u.x), bf2f(u.y), bf2f(u.z), bf2f(u.w));
}

template<typename T> __device__ __forceinline__ void store4(T* p, float4 v);
template<> __device__ __forceinline__ void store4<float>(float* p, float4 v){ *(float4*)p = v; }
template<> __device__ __forceinline__ void store4<bf16>(bf16* p, float4 v){
  union{ ushort4 u; bf16 h[4]; } t;
  t.h[0] = __float2bfloat16(v.x); t.h[1] = __float2bfloat16(v.y);
  t.h[2] = __float2bfloat16(v.z); t.h[3] = __float2bfloat16(v.w);
  *(ushort4*)p = t.u;
}

__device__ __forceinline__ float gelu_exact(float x){
  return 0.5f * x * (1.0f + erff(x * 0.70710678118654752f));
}

// fp32 -> (h1 fp16, h2 fp16) with x ~= h1 + h2/4096 (residual scaled to dodge
// fp16 denormal flush). Captures ~22-24 mantissa bits => fp32-fidelity.
__device__ __forceinline__ void splitf16(float x, unsigned short& u1, unsigned short& u2){
  _Float16 p = (_Float16)x;
  float r = (x - (float)p) * 4096.0f;
  _Float16 q = (_Float16)r;
  union{_Float16 f; unsigned short u;} c1, c2;
  c1.f = p; c2.f = q;
  u1 = c1.u; u2 = c2.u;
}

// ---------------------------------------------------------------------------
// Pre-split pass: fp32 tensor -> two fp16 planes (h1, h2*4096). Memory-bound.
// ---------------------------------------------------------------------------
__global__ __launch_bounds__(256) void split_f16_kernel(
    const float* __restrict__ x, unsigned short* __restrict__ h1,
    unsigned short* __restrict__ h2, int n4)
{
  int i = blockIdx.x * 256 + threadIdx.x;
  const int stride = gridDim.x * 256;
  for (; i < n4; i += stride){
    const float4 v = *(const float4*)(x + (size_t)i*4);
    ushort4 a, b;
    splitf16(v.x, a.x, b.x);
    splitf16(v.y, a.y, b.y);
    splitf16(v.z, a.z, b.z);
    splitf16(v.w, a.w, b.w);
    *(ushort4*)(h1 + (size_t)i*4) = a;
    *(ushort4*)(h2 + (size_t)i*4) = b;
  }
}

// ---------------------------------------------------------------------------
// Generic tiled GEMM: out[M,N] = act(A[M,K] @ W[K,N] + bias [+ res[M,N]])
// 64x64 tile, BK=16, 256 threads, 4x4 micro-tile. M,N % 64 == 0, K % 16 == 0.
// ---------------------------------------------------------------------------
template<typename TIN, typename TOUT, int ACT, bool RES>
__global__ __launch_bounds__(256) void gemm_tile(
    const TIN* __restrict__ A, const float* __restrict__ W,
    const float* __restrict__ bias, const float* __restrict__ res,
    TOUT* __restrict__ out, int M, int N, int K)
{
  __shared__ float As[16][68];   // transposed: As[k][m]
  __shared__ float Bs[16][68];   // Bs[k][n]
  const int tid = threadIdx.x;
  const int tx = tid & 15, ty = tid >> 4;
  const int m0 = blockIdx.y * 64, n0 = blockIdx.x * 64;
  const int am = tid >> 2, ak = (tid & 3) * 4;
  const int bk = tid >> 4, bn = (tid & 15) * 4;
  float c[4][4] = {{0.f,0.f,0.f,0.f},{0.f,0.f,0.f,0.f},{0.f,0.f,0.f,0.f},{0.f,0.f,0.f,0.f}};

  for (int k0 = 0; k0 < K; k0 += 16){
    float4 a4 = load4<TIN>(A + (size_t)(m0+am)*K + (k0+ak));
    As[ak+0][am]=a4.x; As[ak+1][am]=a4.y; As[ak+2][am]=a4.z; As[ak+3][am]=a4.w;
    float4 b4 = *(const float4*)(W + (size_t)(k0+bk)*N + (n0+bn));
    *(float4*)&Bs[bk][bn] = b4;
    __syncthreads();
#pragma unroll
    for (int kk=0; kk<16; kk++){
      const float4 a = *(const float4*)&As[kk][ty*4];
      const float4 b = *(const float4*)&Bs[kk][tx*4];
      const float av[4] = {a.x,a.y,a.z,a.w};
      const float bw[4] = {b.x,b.y,b.z,b.w};
#pragma unroll
      for (int i=0;i<4;i++)
#pragma unroll
        for (int j=0;j<4;j++)
          c[i][j] = fmaf(av[i], bw[j], c[i][j]);
    }
    __syncthreads();
  }

  const float4 bv = *(const float4*)(bias + n0 + tx*4);
#pragma unroll
  for (int i=0;i<4;i++){
    const size_t row = (size_t)(m0 + ty*4 + i);
    float4 v = make_float4(c[i][0]+bv.x, c[i][1]+bv.y, c[i][2]+bv.z, c[i][3]+bv.w);
    if (RES){
      const float4 r = *(const float4*)(res + row*N + n0 + tx*4);
      v.x+=r.x; v.y+=r.y; v.z+=r.z; v.w+=r.w;
    }
    if (ACT==1){ v.x=gelu_exact(v.x); v.y=gelu_exact(v.y); v.z=gelu_exact(v.z); v.w=gelu_exact(v.w); }
    store4<TOUT>(out + row*N + n0 + tx*4, v);
  }
}

// ---------------------------------------------------------------------------
// Saliency via MFMA on split-fp16 planes (h1 + h2/4096, 3 products =
// fp32-fidelity; only dropped term h2*g2 is at 2^-24 relative).
// scores[b,i] = max_j dot(sampled[b,i,:], base[b,j,:]) / sqrt(C)
// Block: 128 sampled rows; 4 waves 2x2; each wave 64x64 (2x2 frags of
// 32x32x16). N loop: 8 tiles of 128 base rows. K staged BK=32; LDS rows
// padded to 40 shorts (80 B) so ds_read_b128 frag reads cycle all 32 banks.
// accH holds h1*g1; accL holds h1*g2 + h2*g1 (carries one 4096 scale).
// C/D layout (verified r0: scores output passed): col=lane&31,
// row=(reg&3)+8*(reg>>2)+4*(lane>>5).
// ---------------------------------------------------------------------------
__global__ __launch_bounds__(256, 2) void saliency_mfma(
    const unsigned short* __restrict__ Ah1g, const unsigned short* __restrict__ Ah2g,
    const unsigned short* __restrict__ Bh1g, const unsigned short* __restrict__ Bh2g,
    float* __restrict__ scores, double* __restrict__ dscores)
{
  const int b = blockIdx.y, it = blockIdx.x;
  __shared__ unsigned short A1[128*40];
  __shared__ unsigned short A2[128*40];
  __shared__ unsigned short B1[128*40];
  __shared__ unsigned short B2[128*40];
  __shared__ float red[128][2];

  const int t = threadIdx.x;
  const int lane = t & 63, w = t >> 6;
  const int wr = w >> 1, wc = w & 1;          // wave grid 2x2
  const int frow = lane & 31;                  // fragment row/col within 32
  const int kgr  = (lane >> 5) * 8;            // fragment k-element group
  const int lr = t >> 2, lc = (t & 3) * 8;     // loader: 64 rows x 4 x ushort8

  const size_t Abase = ((size_t)b*NS + (size_t)it*128) * C_;
  const size_t Bbase = (size_t)b*NB*C_;

  float rmax[2][16];
#pragma unroll
  for (int mi=0;mi<2;mi++)
#pragma unroll
    for (int r=0;r<16;r++) rmax[mi][r] = -3.0e38f;

  for (int jt = 0; jt < NB/128; jt++){
    f32x16 accH[2][2], accL[2][2];
#pragma unroll
    for (int mi=0;mi<2;mi++)
#pragma unroll
      for (int ni=0;ni<2;ni++)
#pragma unroll
        for (int r=0;r<16;r++){ accH[mi][ni][r] = 0.f; accL[mi][ni][r] = 0.f; }

    for (int k0 = 0; k0 < C_; k0 += 32){
      // ---- stage fp16 planes -> LDS (16B vector loads) ----
#pragma unroll
      for (int i=0;i<2;i++){
        const int row = lr + i*64;
        const size_t ga = Abase + (size_t)row*C_ + k0 + lc;
        const size_t gb = Bbase + (size_t)(jt*128 + row)*C_ + k0 + lc;
        const int lo = row*40 + lc;
        *(ushort8*)&A1[lo] = *(const ushort8*)&Ah1g[ga];
        *(ushort8*)&A2[lo] = *(const ushort8*)&Ah2g[ga];
        *(ushort8*)&B1[lo] = *(const ushort8*)&Bh1g[gb];
        *(ushort8*)&B2[lo] = *(const ushort8*)&Bh2g[gb];
      }
      __syncthreads();
      // ---- compute: two k16 sub-steps ----
#pragma unroll
      for (int s=0;s<2;s++){
        half8 a1[2], a2[2], b1[2], b2[2];
#pragma unroll
        for (int mi=0;mi<2;mi++){
          const int ro = (wr*64 + mi*32 + frow)*40 + s*16 + kgr;
          a1[mi] = *(const half8*)&A1[ro];
          a2[mi] = *(const half8*)&A2[ro];
        }
#pragma unroll
        for (int ni=0;ni<2;ni++){
          const int ro = (wc*64 + ni*32 + frow)*40 + s*16 + kgr;
          b1[ni] = *(const half8*)&B1[ro];
          b2[ni] = *(const half8*)&B2[ro];
        }
#pragma unroll
        for (int mi=0;mi<2;mi++)
#pragma unroll
          for (int ni=0;ni<2;ni++){
            accH[mi][ni] = __builtin_amdgcn_mfma_f32_32x32x16_f16(a1[mi], b1[ni], accH[mi][ni], 0, 0, 0);
            accL[mi][ni] = __builtin_amdgcn_mfma_f32_32x32x16_f16(a1[mi], b2[ni], accL[mi][ni], 0, 0, 0);
            accL[mi][ni] = __builtin_amdgcn_mfma_f32_32x32x16_f16(a2[mi], b1[ni], accL[mi][ni], 0, 0, 0);
          }
      }
      __syncthreads();
    }
    // fold this 128-row base tile into the running row max
    const float S2 = 2.44140625e-4f; // 1/4096
#pragma unroll
    for (int mi=0;mi<2;mi++)
#pragma unroll
      for (int ni=0;ni<2;ni++)
#pragma unroll
        for (int r=0;r<16;r++)
          rmax[mi][r] = fmaxf(rmax[mi][r], accH[mi][ni][r] + S2*accL[mi][ni][r]);
  }

  // reduce over the 32 lanes sharing each row (cols lane&31)
#pragma unroll
  for (int off=16; off>=1; off>>=1){
#pragma unroll
    for (int mi=0;mi<2;mi++)
#pragma unroll
      for (int r=0;r<16;r++)
        rmax[mi][r] = fmaxf(rmax[mi][r], __shfl_xor(rmax[mi][r], off, 64));
  }
  if ((lane & 31) == 0){
    const int h = lane >> 5;
#pragma unroll
    for (int mi=0;mi<2;mi++)
#pragma unroll
      for (int r=0;r<16;r++){
        const int lrow = wr*64 + mi*32 + (r&3) + 8*(r>>2) + 4*h;
        red[lrow][wc] = rmax[mi][r];
      }
  }
  __syncthreads();
  if (t < 128){
    const double RSC = 0.036084391824351615; // 1/sqrt(768)
    const float m = fmaxf(red[t][0], red[t][1]);
    const double sc = (double)m * RSC;
    scores[(size_t)b*NS + it*128 + t] = (float)sc;
    dscores[(size_t)b*NS + it*128 + t] = sc;
  }
}

// ---------------------------------------------------------------------------
// Top-k (iterative argmax, k=128) on fp64 scores; tie-break = lowest index.
// One block per batch.
// ---------------------------------------------------------------------------
__global__ __launch_bounds__(256) void topk_kernel(
    const double* __restrict__ dsc, float* __restrict__ topk_f, int* __restrict__ topk_i)
{
  const int b = blockIdx.x, tid = threadIdx.x;
  __shared__ double vals[NS];
  __shared__ int sel[KTOP];
  __shared__ double wv_s[4]; __shared__ int wi_s[4];
  for (int e=0;e<NS/256;e++) vals[e*256+tid] = dsc[(size_t)b*NS + e*256+tid];
  __syncthreads();
  for (int iter=0; iter<KTOP; iter++){
    double bv = -1e300; int bi = 0x7fffffff;
    for (int e=0;e<NS/256;e++){
      int idx = e*256+tid; double v = vals[idx];
      if (v > bv){ bv=v; bi=idx; }
    }
    for (int off=32; off>=1; off>>=1){
      double ov = __shfl_down(bv, off);
      int    oi = __shfl_down(bi, off);
      if (ov > bv || (ov == bv && oi < bi)){ bv=ov; bi=oi; }
    }
    const int lane = tid & 63, w = tid >> 6;
    if (lane==0){ wv_s[w]=bv; wi_s[w]=bi; }
    __syncthreads();
    if (tid==0){
      double fv = wv_s[0]; int fi = wi_s[0];
      for (int t=1;t<4;t++) if (wv_s[t] > fv || (wv_s[t]==fv && wi_s[t]<fi)){ fv=wv_s[t]; fi=wi_s[t]; }
      sel[iter] = fi; vals[fi] = -1e300;
    }
    __syncthreads();
  }
  if (tid < KTOP){
    topk_f[(size_t)b*KTOP + tid] = (float)sel[tid];
    topk_i[b*KTOP + tid] = sel[tid];
  }
}

__global__ __launch_bounds__(192) void gather_kernel(
    const float* __restrict__ sampled, const int* __restrict__ topk_i, float* __restrict__ sel)
{
  const int blk = blockIdx.x; const int b = blk >> 7, kk = blk & 127;
  const int idx = topk_i[b*KTOP + kk];
  const float4* src = (const float4*)(sampled + ((size_t)b*NS + idx)*C_);
  float4* dst = (float4*)(sel + ((size_t)b*KTOP + kk)*C_);
  dst[threadIdx.x] = src[threadIdx.x];
}

// ---------------------------------------------------------------------------
// Attention part 1: logits = q k^T / 8, softmax rows -> attn output.
// Block = (qtile of 64 rows, head, batch). 256 threads: ty=rows/8, tx=keys/4.
// ---------------------------------------------------------------------------
__global__ __launch_bounds__(256) void attn_softmax(
    const bf16* __restrict__ q, const float* __restrict__ kbuf, float* __restrict__ attn)
{
  const int qt = blockIdx.x, h = blockIdx.y, b = blockIdx.z;
  __shared__ float As[16][68];    // q: As[k][row]
  __shared__ float Bs[16][132];   // k: Bs[k][key]
  const int tid = threadIdx.x;
  const int tx = tid & 31, ty = tid >> 5;
  const int am = tid >> 2, ak = (tid & 3)*4;
  const int bm = tid >> 1, bk = (tid & 1)*8;
  float c[8][4] = {{0.f,0.f,0.f,0.f},{0.f,0.f,0.f,0.f},{0.f,0.f,0.f,0.f},{0.f,0.f,0.f,0.f},
                   {0.f,0.f,0.f,0.f},{0.f,0.f,0.f,0.f},{0.f,0.f,0.f,0.f},{0.f,0.f,0.f,0.f}};

  for (int k0 = 0; k0 < DH; k0 += 16){
    float4 a4 = load4<bf16>(q + ((size_t)(b*NB + qt*64 + am))*C_ + h*DH + k0 + ak);
    As[ak+0][am]=a4.x; As[ak+1][am]=a4.y; As[ak+2][am]=a4.z; As[ak+3][am]=a4.w;
    const float* kp = kbuf + ((size_t)(b*KTOP + bm))*C_ + h*DH + k0 + bk;
    float4 b40 = *(const float4*)(kp);
    float4 b41 = *(const float4*)(kp + 4);
    Bs[bk+0][bm]=b40.x; Bs[bk+1][bm]=b40.y; Bs[bk+2][bm]=b40.z; Bs[bk+3][bm]=b40.w;
    Bs[bk+4][bm]=b41.x; Bs[bk+5][bm]=b41.y; Bs[bk+6][bm]=b41.z; Bs[bk+7][bm]=b41.w;
    __syncthreads();
#pragma unroll
    for (int kk=0; kk<16; kk++){
      const float4 a0 = *(const float4*)&As[kk][ty*8];
      const float4 a1 = *(const float4*)&As[kk][ty*8+4];
      const float4 bb = *(const float4*)&Bs[kk][tx*4];
      const float av[8] = {a0.x,a0.y,a0.z,a0.w,a1.x,a1.y,a1.z,a1.w};
      const float bw[4] = {bb.x,bb.y,bb.z,bb.w};
#pragma unroll
      for (int i=0;i<8;i++)
#pragma unroll
        for (int j=0;j<4;j++)
          c[i][j] = fmaf(av[i], bw[j], c[i][j]);
    }
    __syncthreads();
  }

  const float scale = 0.125f; // 1/sqrt(64)
  const size_t obase = (((size_t)b*H_ + h)*NB + (size_t)qt*64)*KTOP;
#pragma unroll
  for (int i=0;i<8;i++){
    float l[4];
#pragma unroll
    for (int j=0;j<4;j++) l[j] = c[i][j]*scale;
    float m = fmaxf(fmaxf(l[0],l[1]), fmaxf(l[2],l[3]));
    for (int off=16; off>=1; off>>=1) m = fmaxf(m, __shfl_xor(m, off, 32));
    float p[4]; float s = 0.f;
#pragma unroll
    for (int j=0;j<4;j++){ p[j] = expf(l[j]-m); s += p[j]; }
    for (int off=16; off>=1; off>>=1) s += __shfl_xor(s, off, 32);
    const float inv = 1.0f / s;
    float4 o = make_float4(p[0]*inv, p[1]*inv, p[2]*inv, p[3]*inv);
    *(float4*)(attn + obase + (size_t)(ty*8+i)*KTOP + tx*4) = o;
  }
}

// ---------------------------------------------------------------------------
// Attention part 2: attended[b,row,h*64+d] = attn[b,h,row,:] @ v[b,:,h*64+d]
// ---------------------------------------------------------------------------
__global__ __launch_bounds__(256) void attn_pv(
    const float* __restrict__ attn, const float* __restrict__ vbuf, bf16* __restrict__ attout)
{
  const int qt = blockIdx.x, h = blockIdx.y, b = blockIdx.z;
  __shared__ float As[16][68];   // attn: As[k][row]
  __shared__ float Bs[16][68];   // v: Bs[k][d]
  const int tid = threadIdx.x;
  const int tx = tid & 15, ty = tid >> 4;
  const int am = tid >> 2, ak = (tid & 3)*4;
  const int bk = tid >> 4, bn = (tid & 15)*4;
  const float* Ab = attn + (((size_t)b*H_ + h)*NB + (size_t)qt*64)*KTOP;
  float c[4][4] = {{0.f,0.f,0.f,0.f},{0.f,0.f,0.f,0.f},{0.f,0.f,0.f,0.f},{0.f,0.f,0.f,0.f}};

  for (int k0 = 0; k0 < KTOP; k0 += 16){
    float4 a4 = *(const float4*)(Ab + (size_t)am*KTOP + k0 + ak);
    As[ak+0][am]=a4.x; As[ak+1][am]=a4.y; As[ak+2][am]=a4.z; As[ak+3][am]=a4.w;
    float4 b4 = *(const float4*)(vbuf + ((size_t)(b*KTOP + k0 + bk))*C_ + h*DH + bn);
    *(float4*)&Bs[bk][bn] = b4;
    __syncthreads();
#pragma unroll
    for (int kk=0; kk<16; kk++){
      const float4 a = *(const float4*)&As[kk][ty*4];
      const float4 bb = *(const float4*)&Bs[kk][tx*4];
      const float av[4] = {a.x,a.y,a.z,a.w};
      const float bw[4] = {bb.x,bb.y,bb.z,bb.w};
#pragma unroll
      for (int i=0;i<4;i++)
#pragma unroll
        for (int j=0;j<4;j++)
          c[i][j] = fmaf(av[i], bw[j], c[i][j]);
    }
    __syncthreads();
  }
#pragma unroll
  for (int i=0;i<4;i++){
    float4 v = make_float4(c[i][0], c[i][1], c[i][2], c[i][3]);
    store4<bf16>(attout + ((size_t)(b*NB + qt*64 + ty*4 + i))*C_ + h*DH + tx*4, v);
  }
}

// ---------------------------------------------------------------------------
// LayerNorm over C=768. One block per row; optional second input (residual).
// ---------------------------------------------------------------------------
__global__ __launch_bounds__(256) void ln_kernel(
    const float* __restrict__ inA, const float* __restrict__ inB,
    const float* __restrict__ g, const float* __restrict__ bb, float* __restrict__ out)
{
  const int row = blockIdx.x, tid = threadIdx.x;
  const size_t base = (size_t)row * C_;
  float x[3];
#pragma unroll
  for (int e=0;e<3;e++){
    const int idx = e*256 + tid;
    x[e] = inA[base+idx] + (inB ? inB[base+idx] : 0.f);
  }
  float s1 = x[0]+x[1]+x[2];
  float s2 = x[0]*x[0]+x[1]*x[1]+x[2]*x[2];
  for (int off=32; off>=1; off>>=1){ s1 += __shfl_down(s1,off); s2 += __shfl_down(s2,off); }
  __shared__ float a1[4], a2[4], st[2];
  const int lane = tid & 63, w = tid >> 6;
  if (lane==0){ a1[w]=s1; a2[w]=s2; }
  __syncthreads();
  if (tid==0){
    float t1 = a1[0]+a1[1]+a1[2]+a1[3];
    float t2 = a2[0]+a2[1]+a2[2]+a2[3];
    float mu = t1 * (1.0f/C_);
    float var = t2 * (1.0f/C_) - mu*mu;
    st[0]=mu; st[1]=rsqrtf(var + EPSV);
  }
  __syncthreads();
  const float mu = st[0], rs = st[1];
#pragma unroll
  for (int e=0;e<3;e++){
    const int idx = e*256+tid;
    out[base+idx] = (x[e]-mu)*rs*g[idx] + bb[idx];
  }
}

// ---------------------------------------------------------------------------
extern "C" void kernel_launch(void* const* d_in, const int* in_sizes, int n_in,
                              void* d_out, int out_size, void* d_ws, size_t ws_size,
                              hipStream_t stream)
{
  const float* base    = (const float*)d_in[0];
  const float* sampled = (const float*)d_in[1];
  const float* Wq = (const float*)d_in[2];  const float* bq = (const float*)d_in[3];
  const float* Wk = (const float*)d_in[4];  const float* bk = (const float*)d_in[5];
  const float* Wv = (const float*)d_in[6];  const float* bv = (const float*)d_in[7];
  const float* Wo = (const float*)d_in[8];  const float* bo = (const float*)d_in[9];
  const float* g1 = (const float*)d_in[10]; const float* b1 = (const float*)d_in[11];
  const float* g2 = (const float*)d_in[12]; const float* b2 = (const float*)d_in[13];
  const float* Wm1 = (const float*)d_in[14]; const float* bm1 = (const float*)d_in[15];
  const float* Wm2 = (const float*)d_in[16]; const float* bm2 = (const float*)d_in[17];

  float* out = (float*)d_out;
  float* o_x      = out;                 // [16,1024,768]
  float* o_scores = out + 12582912;      // [16,4096]
  float* o_attn   = out + 12648448;      // [16,12,1024,128]
  float* o_topk   = out + 37814272;      // [16,128] (as float)
  float* o_sel    = out + 37816320;      // [16,128,768]

  char* ws = (char*)d_ws;
  int*    topk_i = (int*)   (ws);                 // 8 KB
  double* dscore = (double*)(ws + 8192);          // 512 KB
  float*  kbuf   = (float*) (ws + 532480);        // 6 MB
  float*  vbuf   = (float*) (ws + 6823936);       // 6 MB
  bf16*   qbuf   = (bf16*)  (ws + 13115392);      // 24 MB
  bf16*   attbuf = (bf16*)  (ws + 38281216);      // 24 MB
  float*  rbuf   = (float*) (ws + 63447040);      // 48 MB
  bf16*   hbuf   = (bf16*)  (ws + 113778688);     // 96 MB  (end ~214.4 MB)

  // --- saliency scratch (lifetime: steps 0-1 only) ---
  // sampled fp16 planes overlay kbuf..hbuf (written at steps >= 4):
  unsigned short* s_h1 = (unsigned short*)(ws + 532480);               // 100.7 MB
  unsigned short* s_h2 = s_h1 + (size_t)B_*NS*C_;                      // 100.7 MB (end ~201.9 MB)
  // base fp16 planes overlay o_attn (fully rewritten at step 7):
  unsigned short* b_h1 = (unsigned short*)o_attn;                      // 25.2 MB
  unsigned short* b_h2 = b_h1 + (size_t)B_*NB*C_;                      // 25.2 MB

  // 0) pre-split fp32 -> fp16 hi/lo planes (memory-bound)
  split_f16_kernel<<<2048, 256, 0, stream>>>(sampled, s_h1, s_h2, B_*NS*C_/4);
  split_f16_kernel<<<512, 256, 0, stream>>>(base, b_h1, b_h2, B_*NB*C_/4);
  // 1) saliency scores via split-fp16 MFMA (fp32-fidelity)
  saliency_mfma<<<dim3(NS/128, B_), 256, 0, stream>>>(s_h1, s_h2, b_h1, b_h2, o_scores, dscore);
  // 2) top-k
  topk_kernel<<<B_, 256, 0, stream>>>(dscore, o_topk, topk_i);
  // 3) gather selected
  gather_kernel<<<B_*KTOP, 192, 0, stream>>>(sampled, topk_i, o_sel);
  // 4-6) projections
  gemm_tile<float, bf16, 0, false><<<dim3(C_/64, (B_*NB)/64), 256, 0, stream>>>(base, Wq, bq, nullptr, qbuf, B_*NB, C_, C_);
  gemm_tile<float, float, 0, false><<<dim3(C_/64, (B_*KTOP)/64), 256, 0, stream>>>(o_sel, Wk, bk, nullptr, kbuf, B_*KTOP, C_, C_);
  gemm_tile<float, float, 0, false><<<dim3(C_/64, (B_*KTOP)/64), 256, 0, stream>>>(o_sel, Wv, bv, nullptr, vbuf, B_*KTOP, C_, C_);
  // 7) logits + softmax -> attn output (overwrites the base-plane scratch)
  attn_softmax<<<dim3(NB/64, H_, B_), 256, 0, stream>>>(qbuf, kbuf, o_attn);
  // 8) attn @ v
  attn_pv<<<dim3(NB/64, H_, B_), 256, 0, stream>>>(o_attn, vbuf, attbuf);
  // 9) output projection + residual
  gemm_tile<bf16, float, 0, true><<<dim3(C_/64, (B_*NB)/64), 256, 0, stream>>>(attbuf, Wo, bo, base, rbuf, B_*NB, C_, C_);
  // 10) LN1 -> x1 (stored in o_x)
  ln_kernel<<<B_*NB, 256, 0, stream>>>(rbuf, nullptr, g1, b1, o_x);
  // 11) MLP up + GELU
  gemm_tile<float, bf16, 1, false><<<dim3(CM/64, (B_*NB)/64), 256, 0, stream>>>(o_x, Wm1, bm1, nullptr, hbuf, B_*NB, CM, C_);
  // 12) MLP down
  gemm_tile<bf16, float, 0, false><<<dim3(C_/64, (B_*NB)/64), 256, 0, stream>>>(hbuf, Wm2, bm2, nullptr, rbuf, B_*NB, C_, CM);
  // 13) LN2 (x1 + h) -> final x (in-place over o_x)
  ln_kernel<<<B_*NB, 256, 0, stream>>>(rbuf, o_x, g2, b2, o_x);
}

// Round 3
// 1554.862 us; speedup vs baseline: 3.1596x; 2.3564x over previous
//
#include <hip/hip_runtime.h>
#include <hip/hip_bf16.h>

#define B_   16
#define NB   1024
#define NS   4096
#define C_   768
#define H_   12
#define DH   64
#define KTOP 128
#define CM   3072
#define EPSV 1e-5f

typedef __attribute__((ext_vector_type(8))) _Float16 half8;
typedef __attribute__((ext_vector_type(8))) unsigned short ushort8;
typedef __attribute__((ext_vector_type(16))) float f32x16;

__device__ __forceinline__ unsigned short f2h(float x){
  union{_Float16 f; unsigned short u;} c; c.f = (_Float16)x; return c.u;
}
__device__ __forceinline__ float h2f(unsigned short u){
  union{_Float16 f; unsigned short u_;} c; c.u_ = u; return (float)c.f;
}

__device__ __forceinline__ float gelu_exact(float x){
  return 0.5f * x * (1.0f + erff(x * 0.70710678118654752f));
}

// fp32 -> (h1 fp16, h2 fp16) with x ~= h1 + h2/4096 (residual scaled to dodge
// fp16 denormal flush). Captures ~22-24 mantissa bits => fp32-fidelity.
__device__ __forceinline__ void splitf16(float x, unsigned short& u1, unsigned short& u2){
  _Float16 p = (_Float16)x;
  float r = (x - (float)p) * 4096.0f;
  _Float16 q = (_Float16)r;
  union{_Float16 f; unsigned short u;} c1, c2;
  c1.f = p; c2.f = q;
  u1 = c1.u; u2 = c2.u;
}

// ---------------------------------------------------------------------------
// Pre-split pass: fp32 tensor -> two fp16 planes (h1, h2*4096). Memory-bound.
// ---------------------------------------------------------------------------
__global__ __launch_bounds__(256) void split_f16_kernel(
    const float* __restrict__ x, unsigned short* __restrict__ h1,
    unsigned short* __restrict__ h2, int n4)
{
  int i = blockIdx.x * 256 + threadIdx.x;
  const int stride = gridDim.x * 256;
  for (; i < n4; i += stride){
    const float4 v = *(const float4*)(x + (size_t)i*4);
    ushort4 a, b;
    splitf16(v.x, a.x, b.x);
    splitf16(v.y, a.y, b.y);
    splitf16(v.z, a.z, b.z);
    splitf16(v.w, a.w, b.w);
    *(ushort4*)(h1 + (size_t)i*4) = a;
    *(ushort4*)(h2 + (size_t)i*4) = b;
  }
}

// ---------------------------------------------------------------------------
// Weight convert+transpose: W[K][N] fp32 -> Wt[N][K] fp16. 32x32 LDS tiles.
// ---------------------------------------------------------------------------
__global__ __launch_bounds__(256) void wt_f16(
    const float* __restrict__ W, unsigned short* __restrict__ Wt, int K, int N)
{
  __shared__ unsigned short tile[32][33];
  const int kb = blockIdx.y*32, nb = blockIdx.x*32;
  const int tx = threadIdx.x & 31, ty = threadIdx.x >> 5;  // 32 x 8
#pragma unroll
  for (int i=0;i<32;i+=8)
    tile[ty+i][tx] = f2h(W[(size_t)(kb+ty+i)*N + nb+tx]);
  __syncthreads();
#pragma unroll
  for (int i=0;i<32;i+=8)
    Wt[(size_t)(nb+ty+i)*K + kb+tx] = tile[tx][ty+i];
}

// ---------------------------------------------------------------------------
// MFMA GEMM: out[M,N] = act(A[M,K] @ Wt[N,K]^T + bias [+ res]).
// fp16 inputs, fp32 accumulate. 128x128 tile, BK=32, 4 waves 2x2, each wave
// 64x64 as 2x2 frags of 32x32x16_f16. LDS rows padded to 40 shorts (80 B).
// Same verified structure/C-D mapping as saliency_mfma:
//   A/B frag: row|col = lane&31, k = 8*(lane>>5)+e
//   C/D:      col = lane&31, row = (reg&3)+8*(reg>>2)+4*(lane>>5)
// M,N % 128 == 0; K % 32 == 0.
// ---------------------------------------------------------------------------
template<int ACT, bool RES, bool OUT32, bool OUT16>
__global__ __launch_bounds__(256, 2) void gemm_mfma(
    const unsigned short* __restrict__ A, const unsigned short* __restrict__ Bt,
    const float* __restrict__ bias, const float* __restrict__ res,
    float* __restrict__ out32, unsigned short* __restrict__ out16,
    int M, int N, int K)
{
  __shared__ unsigned short A1[128*40];
  __shared__ unsigned short B1[128*40];
  const int t = threadIdx.x;
  const int lane = t & 63, w = t >> 6;
  const int wr = w >> 1, wc = w & 1;
  const int frow = lane & 31, kgr = (lane >> 5) * 8;
  const int lr = t >> 2, lc = (t & 3) * 8;
  const int m0 = blockIdx.y * 128, n0 = blockIdx.x * 128;

  f32x16 acc[2][2];
#pragma unroll
  for (int mi=0;mi<2;mi++)
#pragma unroll
    for (int ni=0;ni<2;ni++)
#pragma unroll
      for (int r=0;r<16;r++) acc[mi][ni][r] = 0.f;

  for (int k0 = 0; k0 < K; k0 += 32){
#pragma unroll
    for (int i=0;i<2;i++){
      const int row = lr + i*64;
      *(ushort8*)&A1[row*40 + lc] = *(const ushort8*)&A[(size_t)(m0+row)*K + k0 + lc];
      *(ushort8*)&B1[row*40 + lc] = *(const ushort8*)&Bt[(size_t)(n0+row)*K + k0 + lc];
    }
    __syncthreads();
#pragma unroll
    for (int s=0;s<2;s++){
      half8 a[2], b[2];
#pragma unroll
      for (int mi=0;mi<2;mi++)
        a[mi] = *(const half8*)&A1[(wr*64 + mi*32 + frow)*40 + s*16 + kgr];
#pragma unroll
      for (int ni=0;ni<2;ni++)
        b[ni] = *(const half8*)&B1[(wc*64 + ni*32 + frow)*40 + s*16 + kgr];
#pragma unroll
      for (int mi=0;mi<2;mi++)
#pragma unroll
        for (int ni=0;ni<2;ni++)
          acc[mi][ni] = __builtin_amdgcn_mfma_f32_32x32x16_f16(a[mi], b[ni], acc[mi][ni], 0, 0, 0);
    }
    __syncthreads();
  }

  const int hi = lane >> 5, col_l = lane & 31;
#pragma unroll
  for (int ni=0;ni<2;ni++){
    const int col = n0 + wc*64 + ni*32 + col_l;
    const float bc = bias[col];
#pragma unroll
    for (int mi=0;mi<2;mi++){
#pragma unroll
      for (int r=0;r<16;r++){
        const int row = m0 + wr*64 + mi*32 + (r&3) + 8*(r>>2) + 4*hi;
        float v = acc[mi][ni][r] + bc;
        if (RES) v += res[(size_t)row*N + col];
        if (ACT==1) v = gelu_exact(v);
        if (OUT32) out32[(size_t)row*N + col] = v;
        if (OUT16) out16[(size_t)row*N + col] = f2h(v);
      }
    }
  }
}

// ---------------------------------------------------------------------------
// Saliency via MFMA on split-fp16 planes (h1 + h2/4096, 3 products =
// fp32-fidelity). scores[b,i] = max_j dot(sampled[b,i,:], base[b,j,:])/sqrt(C)
// (verified passing in round 2)
// ---------------------------------------------------------------------------
__global__ __launch_bounds__(256, 2) void saliency_mfma(
    const unsigned short* __restrict__ Ah1g, const unsigned short* __restrict__ Ah2g,
    const unsigned short* __restrict__ Bh1g, const unsigned short* __restrict__ Bh2g,
    float* __restrict__ scores, double* __restrict__ dscores)
{
  const int b = blockIdx.y, it = blockIdx.x;
  __shared__ unsigned short A1[128*40];
  __shared__ unsigned short A2[128*40];
  __shared__ unsigned short B1[128*40];
  __shared__ unsigned short B2[128*40];
  __shared__ float red[128][2];

  const int t = threadIdx.x;
  const int lane = t & 63, w = t >> 6;
  const int wr = w >> 1, wc = w & 1;          // wave grid 2x2
  const int frow = lane & 31;                  // fragment row/col within 32
  const int kgr  = (lane >> 5) * 8;            // fragment k-element group
  const int lr = t >> 2, lc = (t & 3) * 8;     // loader: 64 rows x 4 x ushort8

  const size_t Abase = ((size_t)b*NS + (size_t)it*128) * C_;
  const size_t Bbase = (size_t)b*NB*C_;

  float rmax[2][16];
#pragma unroll
  for (int mi=0;mi<2;mi++)
#pragma unroll
    for (int r=0;r<16;r++) rmax[mi][r] = -3.0e38f;

  for (int jt = 0; jt < NB/128; jt++){
    f32x16 accH[2][2], accL[2][2];
#pragma unroll
    for (int mi=0;mi<2;mi++)
#pragma unroll
      for (int ni=0;ni<2;ni++)
#pragma unroll
        for (int r=0;r<16;r++){ accH[mi][ni][r] = 0.f; accL[mi][ni][r] = 0.f; }

    for (int k0 = 0; k0 < C_; k0 += 32){
#pragma unroll
      for (int i=0;i<2;i++){
        const int row = lr + i*64;
        const size_t ga = Abase + (size_t)row*C_ + k0 + lc;
        const size_t gb = Bbase + (size_t)(jt*128 + row)*C_ + k0 + lc;
        const int lo = row*40 + lc;
        *(ushort8*)&A1[lo] = *(const ushort8*)&Ah1g[ga];
        *(ushort8*)&A2[lo] = *(const ushort8*)&Ah2g[ga];
        *(ushort8*)&B1[lo] = *(const ushort8*)&Bh1g[gb];
        *(ushort8*)&B2[lo] = *(const ushort8*)&Bh2g[gb];
      }
      __syncthreads();
#pragma unroll
      for (int s=0;s<2;s++){
        half8 a1[2], a2[2], b1[2], b2[2];
#pragma unroll
        for (int mi=0;mi<2;mi++){
          const int ro = (wr*64 + mi*32 + frow)*40 + s*16 + kgr;
          a1[mi] = *(const half8*)&A1[ro];
          a2[mi] = *(const half8*)&A2[ro];
        }
#pragma unroll
        for (int ni=0;ni<2;ni++){
          const int ro = (wc*64 + ni*32 + frow)*40 + s*16 + kgr;
          b1[ni] = *(const half8*)&B1[ro];
          b2[ni] = *(const half8*)&B2[ro];
        }
#pragma unroll
        for (int mi=0;mi<2;mi++)
#pragma unroll
          for (int ni=0;ni<2;ni++){
            accH[mi][ni] = __builtin_amdgcn_mfma_f32_32x32x16_f16(a1[mi], b1[ni], accH[mi][ni], 0, 0, 0);
            accL[mi][ni] = __builtin_amdgcn_mfma_f32_32x32x16_f16(a1[mi], b2[ni], accL[mi][ni], 0, 0, 0);
            accL[mi][ni] = __builtin_amdgcn_mfma_f32_32x32x16_f16(a2[mi], b1[ni], accL[mi][ni], 0, 0, 0);
          }
      }
      __syncthreads();
    }
    const float S2 = 2.44140625e-4f; // 1/4096
#pragma unroll
    for (int mi=0;mi<2;mi++)
#pragma unroll
      for (int ni=0;ni<2;ni++)
#pragma unroll
        for (int r=0;r<16;r++)
          rmax[mi][r] = fmaxf(rmax[mi][r], accH[mi][ni][r] + S2*accL[mi][ni][r]);
  }

#pragma unroll
  for (int off=16; off>=1; off>>=1){
#pragma unroll
    for (int mi=0;mi<2;mi++)
#pragma unroll
      for (int r=0;r<16;r++)
        rmax[mi][r] = fmaxf(rmax[mi][r], __shfl_xor(rmax[mi][r], off, 64));
  }
  if ((lane & 31) == 0){
    const int h = lane >> 5;
#pragma unroll
    for (int mi=0;mi<2;mi++)
#pragma unroll
      for (int r=0;r<16;r++){
        const int lrow = wr*64 + mi*32 + (r&3) + 8*(r>>2) + 4*h;
        red[lrow][wc] = rmax[mi][r];
      }
  }
  __syncthreads();
  if (t < 128){
    const double RSC = 0.036084391824351615; // 1/sqrt(768)
    const float m = fmaxf(red[t][0], red[t][1]);
    const double sc = (double)m * RSC;
    scores[(size_t)b*NS + it*128 + t] = (float)sc;
    dscores[(size_t)b*NS + it*128 + t] = sc;
  }
}

// ---------------------------------------------------------------------------
// Top-k (iterative argmax, k=128) on fp64 scores; tie-break = lowest index.
// ---------------------------------------------------------------------------
__global__ __launch_bounds__(256) void topk_kernel(
    const double* __restrict__ dsc, float* __restrict__ topk_f, int* __restrict__ topk_i)
{
  const int b = blockIdx.x, tid = threadIdx.x;
  __shared__ double vals[NS];
  __shared__ int sel[KTOP];
  __shared__ double wv_s[4]; __shared__ int wi_s[4];
  for (int e=0;e<NS/256;e++) vals[e*256+tid] = dsc[(size_t)b*NS + e*256+tid];
  __syncthreads();
  for (int iter=0; iter<KTOP; iter++){
    double bv = -1e300; int bi = 0x7fffffff;
    for (int e=0;e<NS/256;e++){
      int idx = e*256+tid; double v = vals[idx];
      if (v > bv){ bv=v; bi=idx; }
    }
    for (int off=32; off>=1; off>>=1){
      double ov = __shfl_down(bv, off);
      int    oi = __shfl_down(bi, off);
      if (ov > bv || (ov == bv && oi < bi)){ bv=ov; bi=oi; }
    }
    const int lane = tid & 63, w = tid >> 6;
    if (lane==0){ wv_s[w]=bv; wi_s[w]=bi; }
    __syncthreads();
    if (tid==0){
      double fv = wv_s[0]; int fi = wi_s[0];
      for (int t=1;t<4;t++) if (wv_s[t] > fv || (wv_s[t]==fv && wi_s[t]<fi)){ fv=wv_s[t]; fi=wi_s[t]; }
      sel[iter] = fi; vals[fi] = -1e300;
    }
    __syncthreads();
  }
  if (tid < KTOP){
    topk_f[(size_t)b*KTOP + tid] = (float)sel[tid];
    topk_i[b*KTOP + tid] = sel[tid];
  }
}

// Gather selected tokens: fp32 output (required) + fp16 copy for K/V GEMMs.
__global__ __launch_bounds__(192) void gather_kernel(
    const float* __restrict__ sampled, const int* __restrict__ topk_i,
    float* __restrict__ sel, unsigned short* __restrict__ sel16)
{
  const int blk = blockIdx.x; const int b = blk >> 7, kk = blk & 127;
  const int idx = topk_i[b*KTOP + kk];
  const float4* src = (const float4*)(sampled + ((size_t)b*NS + idx)*C_);
  float4* dst = (float4*)(sel + ((size_t)b*KTOP + kk)*C_);
  const float4 v = src[threadIdx.x];
  dst[threadIdx.x] = v;
  ushort4 u; u.x = f2h(v.x); u.y = f2h(v.y); u.z = f2h(v.z); u.w = f2h(v.w);
  *(ushort4*)(sel16 + ((size_t)b*KTOP + kk)*C_ + threadIdx.x*4) = u;
}

// ---------------------------------------------------------------------------
// Attention part 1: logits = q k^T / 8, softmax rows -> attn output.
// q is fp16 now; kbuf fp32.
// ---------------------------------------------------------------------------
__global__ __launch_bounds__(256) void attn_softmax(
    const unsigned short* __restrict__ q, const float* __restrict__ kbuf, float* __restrict__ attn)
{
  const int qt = blockIdx.x, h = blockIdx.y, b = blockIdx.z;
  __shared__ float As[16][68];    // q: As[k][row]
  __shared__ float Bs[16][132];   // k: Bs[k][key]
  const int tid = threadIdx.x;
  const int tx = tid & 31, ty = tid >> 5;
  const int am = tid >> 2, ak = (tid & 3)*4;
  const int bm = tid >> 1, bk = (tid & 1)*8;
  float c[8][4] = {{0.f,0.f,0.f,0.f},{0.f,0.f,0.f,0.f},{0.f,0.f,0.f,0.f},{0.f,0.f,0.f,0.f},
                   {0.f,0.f,0.f,0.f},{0.f,0.f,0.f,0.f},{0.f,0.f,0.f,0.f},{0.f,0.f,0.f,0.f}};

  for (int k0 = 0; k0 < DH; k0 += 16){
    ushort4 qu = *(const ushort4*)(q + ((size_t)(b*NB + qt*64 + am))*C_ + h*DH + k0 + ak);
    As[ak+0][am]=h2f(qu.x); As[ak+1][am]=h2f(qu.y); As[ak+2][am]=h2f(qu.z); As[ak+3][am]=h2f(qu.w);
    const float* kp = kbuf + ((size_t)(b*KTOP + bm))*C_ + h*DH + k0 + bk;
    float4 b40 = *(const float4*)(kp);
    float4 b41 = *(const float4*)(kp + 4);
    Bs[bk+0][bm]=b40.x; Bs[bk+1][bm]=b40.y; Bs[bk+2][bm]=b40.z; Bs[bk+3][bm]=b40.w;
    Bs[bk+4][bm]=b41.x; Bs[bk+5][bm]=b41.y; Bs[bk+6][bm]=b41.z; Bs[bk+7][bm]=b41.w;
    __syncthreads();
#pragma unroll
    for (int kk=0; kk<16; kk++){
      const float4 a0 = *(const float4*)&As[kk][ty*8];
      const float4 a1 = *(const float4*)&As[kk][ty*8+4];
      const float4 bb = *(const float4*)&Bs[kk][tx*4];
      const float av[8] = {a0.x,a0.y,a0.z,a0.w,a1.x,a1.y,a1.z,a1.w};
      const float bw[4] = {bb.x,bb.y,bb.z,bb.w};
#pragma unroll
      for (int i=0;i<8;i++)
#pragma unroll
        for (int j=0;j<4;j++)
          c[i][j] = fmaf(av[i], bw[j], c[i][j]);
    }
    __syncthreads();
  }

  const float scale = 0.125f; // 1/sqrt(64)
  const size_t obase = (((size_t)b*H_ + h)*NB + (size_t)qt*64)*KTOP;
#pragma unroll
  for (int i=0;i<8;i++){
    float l[4];
#pragma unroll
    for (int j=0;j<4;j++) l[j] = c[i][j]*scale;
    float m = fmaxf(fmaxf(l[0],l[1]), fmaxf(l[2],l[3]));
    for (int off=16; off>=1; off>>=1) m = fmaxf(m, __shfl_xor(m, off, 32));
    float p[4]; float s = 0.f;
#pragma unroll
    for (int j=0;j<4;j++){ p[j] = expf(l[j]-m); s += p[j]; }
    for (int off=16; off>=1; off>>=1) s += __shfl_xor(s, off, 32);
    const float inv = 1.0f / s;
    float4 o = make_float4(p[0]*inv, p[1]*inv, p[2]*inv, p[3]*inv);
    *(float4*)(attn + obase + (size_t)(ty*8+i)*KTOP + tx*4) = o;
  }
}

// ---------------------------------------------------------------------------
// Attention part 2: attended = attn @ v  -> fp16 output for the Wo MFMA GEMM.
// ---------------------------------------------------------------------------
__global__ __launch_bounds__(256) void attn_pv(
    const float* __restrict__ attn, const float* __restrict__ vbuf, unsigned short* __restrict__ attout)
{
  const int qt = blockIdx.x, h = blockIdx.y, b = blockIdx.z;
  __shared__ float As[16][68];   // attn: As[k][row]
  __shared__ float Bs[16][68];   // v: Bs[k][d]
  const int tid = threadIdx.x;
  const int tx = tid & 15, ty = tid >> 4;
  const int am = tid >> 2, ak = (tid & 3)*4;
  const int bk = tid >> 4, bn = (tid & 15)*4;
  const float* Ab = attn + (((size_t)b*H_ + h)*NB + (size_t)qt*64)*KTOP;
  float c[4][4] = {{0.f,0.f,0.f,0.f},{0.f,0.f,0.f,0.f},{0.f,0.f,0.f,0.f},{0.f,0.f,0.f,0.f}};

  for (int k0 = 0; k0 < KTOP; k0 += 16){
    float4 a4 = *(const float4*)(Ab + (size_t)am*KTOP + k0 + ak);
    As[ak+0][am]=a4.x; As[ak+1][am]=a4.y; As[ak+2][am]=a4.z; As[ak+3][am]=a4.w;
    float4 b4 = *(const float4*)(vbuf + ((size_t)(b*KTOP + k0 + bk))*C_ + h*DH + bn);
    *(float4*)&Bs[bk][bn] = b4;
    __syncthreads();
#pragma unroll
    for (int kk=0; kk<16; kk++){
      const float4 a = *(const float4*)&As[kk][ty*4];
      const float4 bb = *(const float4*)&Bs[kk][tx*4];
      const float av[4] = {a.x,a.y,a.z,a.w};
      const float bw[4] = {bb.x,bb.y,bb.z,bb.w};
#pragma unroll
      for (int i=0;i<4;i++)
#pragma unroll
        for (int j=0;j<4;j++)
          c[i][j] = fmaf(av[i], bw[j], c[i][j]);
    }
    __syncthreads();
  }
#pragma unroll
  for (int i=0;i<4;i++){
    ushort4 u;
    u.x = f2h(c[i][0]); u.y = f2h(c[i][1]); u.z = f2h(c[i][2]); u.w = f2h(c[i][3]);
    *(ushort4*)(attout + ((size_t)(b*NB + qt*64 + ty*4 + i))*C_ + h*DH + tx*4) = u;
  }
}

// ---------------------------------------------------------------------------
// LayerNorm over C=768. Optional residual input; optional fp16 secondary out.
// ---------------------------------------------------------------------------
__global__ __launch_bounds__(256) void ln_kernel(
    const float* __restrict__ inA, const float* __restrict__ inB,
    const float* __restrict__ g, const float* __restrict__ bb,
    float* __restrict__ out, unsigned short* __restrict__ out16)
{
  const int row = blockIdx.x, tid = threadIdx.x;
  const size_t base = (size_t)row * C_;
  float x[3];
#pragma unroll
  for (int e=0;e<3;e++){
    const int idx = e*256 + tid;
    x[e] = inA[base+idx] + (inB ? inB[base+idx] : 0.f);
  }
  float s1 = x[0]+x[1]+x[2];
  float s2 = x[0]*x[0]+x[1]*x[1]+x[2]*x[2];
  for (int off=32; off>=1; off>>=1){ s1 += __shfl_down(s1,off); s2 += __shfl_down(s2,off); }
  __shared__ float a1[4], a2[4], st[2];
  const int lane = tid & 63, w = tid >> 6;
  if (lane==0){ a1[w]=s1; a2[w]=s2; }
  __syncthreads();
  if (tid==0){
    float t1 = a1[0]+a1[1]+a1[2]+a1[3];
    float t2 = a2[0]+a2[1]+a2[2]+a2[3];
    float mu = t1 * (1.0f/C_);
    float var = t2 * (1.0f/C_) - mu*mu;
    st[0]=mu; st[1]=rsqrtf(var + EPSV);
  }
  __syncthreads();
  const float mu = st[0], rs = st[1];
#pragma unroll
  for (int e=0;e<3;e++){
    const int idx = e*256+tid;
    const float v = (x[e]-mu)*rs*g[idx] + bb[idx];
    out[base+idx] = v;
    if (out16) out16[base+idx] = f2h(v);
  }
}

// ---------------------------------------------------------------------------
extern "C" void kernel_launch(void* const* d_in, const int* in_sizes, int n_in,
                              void* d_out, int out_size, void* d_ws, size_t ws_size,
                              hipStream_t stream)
{
  const float* base    = (const float*)d_in[0];
  const float* sampled = (const float*)d_in[1];
  const float* Wq = (const float*)d_in[2];  const float* bq = (const float*)d_in[3];
  const float* Wk = (const float*)d_in[4];  const float* bk = (const float*)d_in[5];
  const float* Wv = (const float*)d_in[6];  const float* bv = (const float*)d_in[7];
  const float* Wo = (const float*)d_in[8];  const float* bo = (const float*)d_in[9];
  const float* g1 = (const float*)d_in[10]; const float* b1 = (const float*)d_in[11];
  const float* g2 = (const float*)d_in[12]; const float* b2 = (const float*)d_in[13];
  const float* Wm1 = (const float*)d_in[14]; const float* bm1 = (const float*)d_in[15];
  const float* Wm2 = (const float*)d_in[16]; const float* bm2 = (const float*)d_in[17];

  float* out = (float*)d_out;
  float* o_x      = out;                 // [16,1024,768]
  float* o_scores = out + 12582912;      // [16,4096]
  float* o_attn   = out + 12648448;      // [16,12,1024,128]
  float* o_topk   = out + 37814272;      // [16,128] (as float)
  float* o_sel    = out + 37816320;      // [16,128,768]

  char* ws = (char*)d_ws;
  int*    topk_i = (int*)   (ws);                 // 8 KB
  double* dscore = (double*)(ws + 8192);          // 512 KB -> 532480
  float*  kbuf   = (float*) (ws + 532480);        // 6 MB   -> 6823936
  float*  vbuf   = (float*) (ws + 6823936);       // 6 MB   -> 13115392
  // 25.2 MB region time-shared: qbuf16 (4->7), attbuf16 (8->9), x16 (10->11)
  unsigned short* qbuf16   = (unsigned short*)(ws + 13115392);   // -> 38281216
  unsigned short* attbuf16 = qbuf16;
  unsigned short* x16      = qbuf16;
  float*  rbuf   = (float*) (ws + 38281216);      // 50.3 MB -> 88612864
  // fp16 weights (transposed [N][K])
  unsigned short* Wq16  = (unsigned short*)(ws + 88612864);
  unsigned short* Wk16  = Wq16  + 589824;
  unsigned short* Wv16  = Wk16  + 589824;
  unsigned short* Wo16  = Wv16  + 589824;
  unsigned short* Wm116 = Wo16  + 589824;   // 768*3072
  unsigned short* Wm216 = Wm116 + 2359296;  // 3072*768  -> byte 102768640
  unsigned short* sel16 = Wm216 + 2359296;  // 2048*768  -> byte 105914368
  // saliency fp16 planes (steps 0-1) overlaid later by hbuf16 (steps 11-12)
  unsigned short* s_h1  = sel16 + 1572864;  // 50.3 MB
  unsigned short* s_h2  = s_h1 + (size_t)B_*NS*C_;  // 50.3 MB -> ~206.6 MB end
  unsigned short* hbuf16 = s_h1;            // [16384][3072] fp16, overlay
  // base fp16 planes live in o_attn (overwritten at step 7)
  unsigned short* b_h1 = (unsigned short*)o_attn;
  unsigned short* b_h2 = b_h1 + (size_t)B_*NB*C_;

  // 0) pre-split fp32 -> fp16 hi/lo planes; weight fp16 transposes
  split_f16_kernel<<<2048, 256, 0, stream>>>(sampled, s_h1, s_h2, B_*NS*C_/4);
  split_f16_kernel<<<512, 256, 0, stream>>>(base, b_h1, b_h2, B_*NB*C_/4);
  wt_f16<<<dim3(C_/32, C_/32), 256, 0, stream>>>(Wq, Wq16, C_, C_);
  wt_f16<<<dim3(C_/32, C_/32), 256, 0, stream>>>(Wk, Wk16, C_, C_);
  wt_f16<<<dim3(C_/32, C_/32), 256, 0, stream>>>(Wv, Wv16, C_, C_);
  wt_f16<<<dim3(C_/32, C_/32), 256, 0, stream>>>(Wo, Wo16, C_, C_);
  wt_f16<<<dim3(CM/32, C_/32), 256, 0, stream>>>(Wm1, Wm116, C_, CM);
  wt_f16<<<dim3(C_/32, CM/32), 256, 0, stream>>>(Wm2, Wm216, CM, C_);
  // 1) saliency scores via split-fp16 MFMA (fp32-fidelity)
  saliency_mfma<<<dim3(NS/128, B_), 256, 0, stream>>>(s_h1, s_h2, b_h1, b_h2, o_scores, dscore);
  // 2) top-k
  topk_kernel<<<B_, 256, 0, stream>>>(dscore, o_topk, topk_i);
  // 3) gather selected (fp32 output + fp16 copy)
  gather_kernel<<<B_*KTOP, 192, 0, stream>>>(sampled, topk_i, o_sel, sel16);
  // 4) Q projection (A = fp16 base plane from saliency pre-split)
  gemm_mfma<0,false,false,true><<<dim3(C_/128, (B_*NB)/128), 256, 0, stream>>>(
      b_h1, Wq16, bq, nullptr, nullptr, qbuf16, B_*NB, C_, C_);
  // 5-6) K/V projections
  gemm_mfma<0,false,true,false><<<dim3(C_/128, (B_*KTOP)/128), 256, 0, stream>>>(
      sel16, Wk16, bk, nullptr, kbuf, nullptr, B_*KTOP, C_, C_);
  gemm_mfma<0,false,true,false><<<dim3(C_/128, (B_*KTOP)/128), 256, 0, stream>>>(
      sel16, Wv16, bv, nullptr, vbuf, nullptr, B_*KTOP, C_, C_);
  // 7) logits + softmax -> attn output (overwrites base-plane scratch)
  attn_softmax<<<dim3(NB/64, H_, B_), 256, 0, stream>>>(qbuf16, kbuf, o_attn);
  // 8) attn @ v -> fp16
  attn_pv<<<dim3(NB/64, H_, B_), 256, 0, stream>>>(o_attn, vbuf, attbuf16);
  // 9) output projection + residual
  gemm_mfma<0,true,true,false><<<dim3(C_/128, (B_*NB)/128), 256, 0, stream>>>(
      attbuf16, Wo16, bo, base, rbuf, nullptr, B_*NB, C_, C_);
  // 10) LN1 -> o_x (fp32) + x16 (fp16)
  ln_kernel<<<B_*NB, 256, 0, stream>>>(rbuf, nullptr, g1, b1, o_x, x16);
  // 11) MLP up + GELU -> fp16
  gemm_mfma<1,false,false,true><<<dim3(CM/128, (B_*NB)/128), 256, 0, stream>>>(
      x16, Wm116, bm1, nullptr, nullptr, hbuf16, B_*NB, CM, C_);
  // 12) MLP down
  gemm_mfma<0,false,true,false><<<dim3(C_/128, (B_*NB)/128), 256, 0, stream>>>(
      hbuf16, Wm216, bm2, nullptr, rbuf, nullptr, B_*NB, C_, CM);
  // 13) LN2 (x1 + h) -> final x
  ln_kernel<<<B_*NB, 256, 0, stream>>>(rbuf, o_x, g2, b2, o_x, nullptr);
}